// Round 3
// baseline (129.801 us; speedup 1.0000x reference)
//
#include <hip/hip_runtime.h>

namespace {

constexpr int FHc = 3, FWc = 3;
constexpr int Bc = 8, Cc = 32, Hc = 32, Wc = 32, Oc = 64;
constexpr int HOc = 30, WOc = 30;
constexpr float SHIFTc = 0.1f;
constexpr int ROWW = 12;                 // padded LDS row (10 used) -> 48B, float4-aligned
constexpr int TILE_F = Cc * FHc * ROWW;  // 1152 floats per (lp|ln) tile

#define LOADROW(dst, base) do {                                         \
    const float4 _a = *reinterpret_cast<const float4*>(base);           \
    const float4 _b = *reinterpret_cast<const float4*>((base) + 4);     \
    const float2 _c = *reinterpret_cast<const float2*>((base) + 8);     \
    dst[0]=_a.x; dst[1]=_a.y; dst[2]=_a.z; dst[3]=_a.w;                 \
    dst[4]=_b.x; dst[5]=_b.y; dst[6]=_b.z; dst[7]=_b.w;                 \
    dst[8]=_c.x; dst[9]=_c.y; } while (0)

__global__ __launch_bounds__(512, 8)   // pin VGPR<=64 -> 8 waves/SIMD -> 4 blocks/CU
void bipolar_morph2d(const float* __restrict__ x,
                     const float* __restrict__ k1,
                     const float* __restrict__ k2,
                     const float* __restrict__ bias,
                     float* __restrict__ out)
{
    // 32 KiB shared: lp/ln tile (2*1152 floats) first, then an 8192-float
    // partial-max buffer reused in two reduction phases.
    __shared__ float sh[8192];
    float* lp = sh;
    float* ln = sh + TILE_F;

    const int tid = threadIdx.x;
    const int bid = blockIdx.x;
    const int wt  = bid & 3;             // which wo-tile of 8
    const int ho  = (bid >> 2) % HOc;
    const int b   = bid / (4 * HOc);
    const int wo0 = wt * 8;

    // ---- stage: lp = log(max(x,0.1)), ln = log(max(-x,0.1)) for 3x10 x C halo ----
    for (int e = tid; e < Cc * FHc * 10; e += 512) {
        const int c   = e / 30;
        const int rem = e - c * 30;
        const int i   = rem / 10;
        const int w   = rem - i * 10;
        int col = wo0 + w; if (col > Wc - 1) col = Wc - 1;   // clamp (only wt==3, s>=6 -> unused)
        const float xv = x[((b * Cc + c) * Hc + (ho + i)) * Wc + col];
        lp[(c * FHc + i) * ROWW + w] = __logf(fmaxf(xv,  SHIFTc));
        ln[(c * FHc + i) * ROWW + w] = __logf(fmaxf(-xv, SHIFTc));
    }
    __syncthreads();

    const int wv    = tid >> 6;   // wave id 0..7: owns c-chunk [4*wv, 4*wv+4)
    const int o     = tid & 63;   // lane = output channel
    const int cbase = wv * 4;

    float m11[8], m12[8], m21[8], m22[8];
    #pragma unroll
    for (int s = 0; s < 8; ++s) m11[s] = m12[s] = m21[s] = m22[s] = -1e30f;

    // one channel, one row at a time: 10 row regs reused for lp then ln pass
    #pragma unroll 1
    for (int c = cbase; c < cbase + 4; ++c) {
        #pragma unroll
        for (int i = 0; i < FHc; ++i) {
            // k taps for this (c,i): j-stride in elements is FWc*... = Cc*Oc = 2048
            const int p0 = (i * FWc * Cc + c) * Oc + o;
            const float k1j0 = k1[p0], k1j1 = k1[p0 + Cc * Oc], k1j2 = k1[p0 + 2 * Cc * Oc];
            const float k2j0 = k2[p0], k2j1 = k2[p0 + Cc * Oc], k2j2 = k2[p0 + 2 * Cc * Oc];

            float r[10];
            LOADROW(r, &lp[(c * FHc + i) * ROWW]);
            #pragma unroll
            for (int s = 0; s < 8; ++s) {
                // fmaxf(fmaxf(a0,a1),a2) -> v_max3_f32, then fold into acc
                m11[s] = fmaxf(m11[s], fmaxf(fmaxf(r[s] + k1j0, r[s + 1] + k1j1), r[s + 2] + k1j2));
                m12[s] = fmaxf(m12[s], fmaxf(fmaxf(r[s] + k2j0, r[s + 1] + k2j1), r[s + 2] + k2j2));
            }
            LOADROW(r, &ln[(c * FHc + i) * ROWW]);
            #pragma unroll
            for (int s = 0; s < 8; ++s) {
                m21[s] = fmaxf(m21[s], fmaxf(fmaxf(r[s] + k1j0, r[s + 1] + k1j1), r[s + 2] + k1j2));
                m22[s] = fmaxf(m22[s], fmaxf(fmaxf(r[s] + k2j0, r[s + 1] + k2j1), r[s + 2] + k2j2));
            }
        }
    }

    // ---- cross-wave max reduction: 8 waves -> 4 -> 1, reusing one 32 KiB buffer ----
    __syncthreads();   // tile reads done; safe to overwrite sh

    // Phase A: upper 4 waves publish, lower 4 merge into registers.
    if (wv >= 4) {
        const int lw = wv - 4;
        #pragma unroll
        for (int s = 0; s < 8; ++s) {
            sh[((lw * 4 + 0) * 8 + s) * 64 + o] = m11[s];
            sh[((lw * 4 + 1) * 8 + s) * 64 + o] = m12[s];
            sh[((lw * 4 + 2) * 8 + s) * 64 + o] = m21[s];
            sh[((lw * 4 + 3) * 8 + s) * 64 + o] = m22[s];
        }
    }
    __syncthreads();
    if (wv < 4) {
        #pragma unroll
        for (int s = 0; s < 8; ++s) {
            m11[s] = fmaxf(m11[s], sh[((wv * 4 + 0) * 8 + s) * 64 + o]);
            m12[s] = fmaxf(m12[s], sh[((wv * 4 + 1) * 8 + s) * 64 + o]);
            m21[s] = fmaxf(m21[s], sh[((wv * 4 + 2) * 8 + s) * 64 + o]);
            m22[s] = fmaxf(m22[s], sh[((wv * 4 + 3) * 8 + s) * 64 + o]);
        }
    }
    __syncthreads();
    // Phase B: lower 4 waves publish merged partials.
    if (wv < 4) {
        #pragma unroll
        for (int s = 0; s < 8; ++s) {
            sh[((wv * 4 + 0) * 8 + s) * 64 + o] = m11[s];
            sh[((wv * 4 + 1) * 8 + s) * 64 + o] = m12[s];
            sh[((wv * 4 + 2) * 8 + s) * 64 + o] = m21[s];
            sh[((wv * 4 + 3) * 8 + s) * 64 + o] = m22[s];
        }
    }
    __syncthreads();

    // ---- finalize: each wave owns one spatial position s = wv ----
    const int s  = wv;
    const int wo = wo0 + s;
    if (wo < WOc) {
        const float bo = bias[o];
        float f[4];
        #pragma unroll
        for (int br = 0; br < 4; ++br) {
            const float v0 = sh[((0 * 4 + br) * 8 + s) * 64 + o];
            const float v1 = sh[((1 * 4 + br) * 8 + s) * 64 + o];
            const float v2 = sh[((2 * 4 + br) * 8 + s) * 64 + o];
            const float v3 = sh[((3 * 4 + br) * 8 + s) * 64 + o];
            f[br] = fmaxf(fmaxf(v0, v1), fmaxf(v2, v3));
        }
        out[((b * Oc + o) * HOc + ho) * WOc + wo] =
            __expf(f[0]) - __expf(f[1]) - __expf(f[2]) + __expf(f[3]) + bo;
    }
}

} // namespace

extern "C" void kernel_launch(void* const* d_in, const int* in_sizes, int n_in,
                              void* d_out, int out_size, void* d_ws, size_t ws_size,
                              hipStream_t stream) {
    const float* x    = (const float*)d_in[0];
    const float* k1   = (const float*)d_in[1];
    const float* k2   = (const float*)d_in[2];
    const float* bias = (const float*)d_in[3];
    float* out        = (float*)d_out;

    const int nblocks = Bc * HOc * 4;   // 8 * 30 * 4 = 960
    bipolar_morph2d<<<dim3(nblocks), dim3(512), 0, stream>>>(x, k1, k2, bias, out);
}

// Round 4
// 68.476 us; speedup vs baseline: 1.8956x; 1.8956x over previous
//
#include <hip/hip_runtime.h>

namespace {

constexpr int FHc = 3, FWc = 3;
constexpr int Bc = 8, Cc = 32, Hc = 32, Wc = 32, Oc = 64;
constexpr int HOc = 30, WOc = 30;
constexpr float SHIFTc = 0.1f;
constexpr int SW = 4;                    // spatial wo-positions per block
constexpr int RW = SW + FWc - 1;         // 6 used floats per LDS row
constexpr int ROWW = 8;                  // padded row -> 32B, float4-aligned
constexpr int TILE_F = Cc * FHc * ROWW;  // 768 floats per (lp|ln) tile

// 6-float row load: float4 + float2 (base 32B-aligned)
#define LOADROW6(dst, base) do {                                        \
    const float4 _a = *reinterpret_cast<const float4*>(base);           \
    const float2 _b = *reinterpret_cast<const float2*>((base) + 4);     \
    dst[0]=_a.x; dst[1]=_a.y; dst[2]=_a.z; dst[3]=_a.w;                 \
    dst[4]=_b.x; dst[5]=_b.y; } while (0)

__global__ __launch_bounds__(256, 8)   // robust under either 2nd-arg semantics:
                                       // -> 32 waves/CU, VGPR cap 64, no spill (live ~50)
void bipolar_morph2d(const float* __restrict__ x,
                     const float* __restrict__ k1,
                     const float* __restrict__ k2,
                     const float* __restrict__ bias,
                     float* __restrict__ out)
{
    // 16 KiB shared: lp/ln tile (2*768 floats) first, then the 4096-float
    // cross-wave partial-max buffer (4 waves * 4 branches * 4 s * 64 o).
    __shared__ float sh[4096];
    float* lp = sh;
    float* ln = sh + TILE_F;

    const int tid = threadIdx.x;
    const int bid = blockIdx.x;
    const int wt  = bid & 7;              // which wo-tile of 4
    const int ho  = (bid >> 3) % HOc;
    const int b   = bid / (8 * HOc);
    const int wo0 = wt * SW;

    // ---- stage: lp = log(max(x,0.1)), ln = log(max(-x,0.1)) for 3 x RW x C halo ----
    for (int e = tid; e < Cc * FHc * RW; e += 256) {
        const int c   = e / (FHc * RW);
        const int rem = e - c * (FHc * RW);
        const int i   = rem / RW;
        const int w   = rem - i * RW;
        int col = wo0 + w; if (col > Wc - 1) col = Wc - 1;  // clamp (only feeds invalid s)
        const float xv = x[((b * Cc + c) * Hc + (ho + i)) * Wc + col];
        lp[(c * FHc + i) * ROWW + w] = __logf(fmaxf(xv,  SHIFTc));
        ln[(c * FHc + i) * ROWW + w] = __logf(fmaxf(-xv, SHIFTc));
    }
    __syncthreads();

    const int wv    = tid >> 6;   // wave id 0..3: owns c-chunk [8*wv, 8*wv+8)
    const int o     = tid & 63;   // lane = output channel
    const int cbase = wv * 8;

    float m11[SW], m12[SW], m21[SW], m22[SW];
    #pragma unroll
    for (int s = 0; s < SW; ++s) m11[s] = m12[s] = m21[s] = m22[s] = -1e30f;

    // one channel, one row at a time: 6 row regs reused for lp then ln pass
    #pragma unroll 1
    for (int c = cbase; c < cbase + 8; ++c) {
        #pragma unroll
        for (int i = 0; i < FHc; ++i) {
            // k taps for this (c,i): j-stride in elements is Cc*Oc = 2048
            const int p0 = (i * FWc * Cc + c) * Oc + o;
            const float k1j0 = k1[p0], k1j1 = k1[p0 + Cc * Oc], k1j2 = k1[p0 + 2 * Cc * Oc];
            const float k2j0 = k2[p0], k2j1 = k2[p0 + Cc * Oc], k2j2 = k2[p0 + 2 * Cc * Oc];

            float r[RW];
            LOADROW6(r, &lp[(c * FHc + i) * ROWW]);
            #pragma unroll
            for (int s = 0; s < SW; ++s) {
                // max3(a0,a1,a2) -> v_max3_f32, then fold into acc
                m11[s] = fmaxf(m11[s], fmaxf(fmaxf(r[s] + k1j0, r[s + 1] + k1j1), r[s + 2] + k1j2));
                m12[s] = fmaxf(m12[s], fmaxf(fmaxf(r[s] + k2j0, r[s + 1] + k2j1), r[s + 2] + k2j2));
            }
            LOADROW6(r, &ln[(c * FHc + i) * ROWW]);
            #pragma unroll
            for (int s = 0; s < SW; ++s) {
                m21[s] = fmaxf(m21[s], fmaxf(fmaxf(r[s] + k1j0, r[s + 1] + k1j1), r[s + 2] + k1j2));
                m22[s] = fmaxf(m22[s], fmaxf(fmaxf(r[s] + k2j0, r[s + 1] + k2j1), r[s + 2] + k2j2));
            }
        }
    }

    // ---- cross-wave max reduction via LDS (reuse tile buffer) ----
    __syncthreads();   // tile reads done; safe to overwrite sh
    #pragma unroll
    for (int s = 0; s < SW; ++s) {
        sh[((wv * 4 + 0) * SW + s) * 64 + o] = m11[s];
        sh[((wv * 4 + 1) * SW + s) * 64 + o] = m12[s];
        sh[((wv * 4 + 2) * SW + s) * 64 + o] = m21[s];
        sh[((wv * 4 + 3) * SW + s) * 64 + o] = m22[s];
    }
    __syncthreads();

    // ---- finalize: each wave owns one spatial position s = wv ----
    const int s  = wv;
    const int wo = wo0 + s;
    if (wo < WOc) {
        const float bo = bias[o];
        float f[4];
        #pragma unroll
        for (int br = 0; br < 4; ++br) {
            const float v0 = sh[((0 * 4 + br) * SW + s) * 64 + o];
            const float v1 = sh[((1 * 4 + br) * SW + s) * 64 + o];
            const float v2 = sh[((2 * 4 + br) * SW + s) * 64 + o];
            const float v3 = sh[((3 * 4 + br) * SW + s) * 64 + o];
            f[br] = fmaxf(fmaxf(v0, v1), fmaxf(v2, v3));
        }
        out[((b * Oc + o) * HOc + ho) * WOc + wo] =
            __expf(f[0]) - __expf(f[1]) - __expf(f[2]) + __expf(f[3]) + bo;
    }
}

} // namespace

extern "C" void kernel_launch(void* const* d_in, const int* in_sizes, int n_in,
                              void* d_out, int out_size, void* d_ws, size_t ws_size,
                              hipStream_t stream) {
    const float* x    = (const float*)d_in[0];
    const float* k1   = (const float*)d_in[1];
    const float* k2   = (const float*)d_in[2];
    const float* bias = (const float*)d_in[3];
    float* out        = (float*)d_out;

    const int nblocks = Bc * HOc * 8;   // 8 * 30 * 8 = 1920 (wo tiles of 4)
    bipolar_morph2d<<<dim3(nblocks), dim3(256), 0, stream>>>(x, k1, k2, bias, out);
}

// Round 5
// 31.672 us; speedup vs baseline: 4.0983x; 2.1620x over previous
//
#include <hip/hip_runtime.h>

namespace {

constexpr int FHc = 3, FWc = 3;
constexpr int Bc = 8, Cc = 32, Hc = 32, Wc = 32, Oc = 64;
constexpr int HOc = 30, WOc = 30;
constexpr float SHIFTc = 0.1f;
constexpr int SW = 4;                    // spatial wo-positions per block
constexpr int RW = SW + FWc - 1;         // 6 used floats per LDS row
constexpr int ROWW = 8;                  // padded row -> 32B, float4-aligned
constexpr int TILE_F = Cc * FHc * ROWW;  // 768 floats per (lp|ln) tile

// 6-float row load: float4 + float2 (base 32B-aligned)
#define LOADROW6(dst, base) do {                                        \
    const float4 _a = *reinterpret_cast<const float4*>(base);           \
    const float2 _b = *reinterpret_cast<const float2*>((base) + 4);     \
    dst[0]=_a.x; dst[1]=_a.y; dst[2]=_a.z; dst[3]=_a.w;                 \
    dst[4]=_b.x; dst[5]=_b.y; } while (0)

// Empirical hipcc formula on gfx950 (R3/R4 evidence): VGPR cap = 256 / <2nd arg>.
// (512,8) -> 32, (256,8) -> 32 (both spilled). (256,4) -> cap 64: live state ~45
// fits, and <=64 VGPR gives 8 waves/EU -> 8 blocks/CU -> whole 1920-block grid
// resident in one round.
__global__ __launch_bounds__(256, 4)
void bipolar_morph2d(const float* __restrict__ x,
                     const float* __restrict__ k1,
                     const float* __restrict__ k2,
                     const float* __restrict__ bias,
                     float* __restrict__ out)
{
    // 16 KiB shared: lp/ln tile (2*768 floats) first, then the 4096-float
    // cross-wave partial-max buffer (4 waves * 4 branches * 4 s * 64 o).
    __shared__ float sh[4096];
    float* lp = sh;
    float* ln = sh + TILE_F;

    const int tid = threadIdx.x;
    const int bid = blockIdx.x;
    const int wt  = bid & 7;              // which wo-tile of 4
    const int ho  = (bid >> 3) % HOc;
    const int b   = bid / (8 * HOc);
    const int wo0 = wt * SW;

    // ---- stage: lp = log(max(x,0.1)), ln = log(max(-x,0.1)) for 3 x RW x C halo ----
    for (int e = tid; e < Cc * FHc * RW; e += 256) {
        const int c   = e / (FHc * RW);
        const int rem = e - c * (FHc * RW);
        const int i   = rem / RW;
        const int w   = rem - i * RW;
        int col = wo0 + w; if (col > Wc - 1) col = Wc - 1;  // clamp (only feeds invalid s)
        const float xv = x[((b * Cc + c) * Hc + (ho + i)) * Wc + col];
        lp[(c * FHc + i) * ROWW + w] = __logf(fmaxf(xv,  SHIFTc));
        ln[(c * FHc + i) * ROWW + w] = __logf(fmaxf(-xv, SHIFTc));
    }
    __syncthreads();

    const int wv    = tid >> 6;   // wave id 0..3: owns c-chunk [8*wv, 8*wv+8)
    const int o     = tid & 63;   // lane = output channel
    const int cbase = wv * 8;

    float m11[SW], m12[SW], m21[SW], m22[SW];
    #pragma unroll
    for (int s = 0; s < SW; ++s) m11[s] = m12[s] = m21[s] = m22[s] = -1e30f;

    // one channel, one row at a time: 6 row regs reused for lp then ln pass
    #pragma unroll 1
    for (int c = cbase; c < cbase + 8; ++c) {
        #pragma unroll
        for (int i = 0; i < FHc; ++i) {
            // k taps for this (c,i): j-stride in elements is Cc*Oc = 2048
            const int p0 = (i * FWc * Cc + c) * Oc + o;
            const float k1j0 = k1[p0], k1j1 = k1[p0 + Cc * Oc], k1j2 = k1[p0 + 2 * Cc * Oc];
            const float k2j0 = k2[p0], k2j1 = k2[p0 + Cc * Oc], k2j2 = k2[p0 + 2 * Cc * Oc];

            float r[RW];
            LOADROW6(r, &lp[(c * FHc + i) * ROWW]);
            #pragma unroll
            for (int s = 0; s < SW; ++s) {
                // max3(a0,a1,a2) -> v_max3_f32, then fold into acc
                m11[s] = fmaxf(m11[s], fmaxf(fmaxf(r[s] + k1j0, r[s + 1] + k1j1), r[s + 2] + k1j2));
                m12[s] = fmaxf(m12[s], fmaxf(fmaxf(r[s] + k2j0, r[s + 1] + k2j1), r[s + 2] + k2j2));
            }
            LOADROW6(r, &ln[(c * FHc + i) * ROWW]);
            #pragma unroll
            for (int s = 0; s < SW; ++s) {
                m21[s] = fmaxf(m21[s], fmaxf(fmaxf(r[s] + k1j0, r[s + 1] + k1j1), r[s + 2] + k1j2));
                m22[s] = fmaxf(m22[s], fmaxf(fmaxf(r[s] + k2j0, r[s + 1] + k2j1), r[s + 2] + k2j2));
            }
        }
    }

    // ---- cross-wave max reduction via LDS (reuse tile buffer) ----
    __syncthreads();   // tile reads done; safe to overwrite sh
    #pragma unroll
    for (int s = 0; s < SW; ++s) {
        sh[((wv * 4 + 0) * SW + s) * 64 + o] = m11[s];
        sh[((wv * 4 + 1) * SW + s) * 64 + o] = m12[s];
        sh[((wv * 4 + 2) * SW + s) * 64 + o] = m21[s];
        sh[((wv * 4 + 3) * SW + s) * 64 + o] = m22[s];
    }
    __syncthreads();

    // ---- finalize: each wave owns one spatial position s = wv ----
    const int s  = wv;
    const int wo = wo0 + s;
    if (wo < WOc) {
        const float bo = bias[o];
        float f[4];
        #pragma unroll
        for (int br = 0; br < 4; ++br) {
            const float v0 = sh[((0 * 4 + br) * SW + s) * 64 + o];
            const float v1 = sh[((1 * 4 + br) * SW + s) * 64 + o];
            const float v2 = sh[((2 * 4 + br) * SW + s) * 64 + o];
            const float v3 = sh[((3 * 4 + br) * SW + s) * 64 + o];
            f[br] = fmaxf(fmaxf(v0, v1), fmaxf(v2, v3));
        }
        out[((b * Oc + o) * HOc + ho) * WOc + wo] =
            __expf(f[0]) - __expf(f[1]) - __expf(f[2]) + __expf(f[3]) + bo;
    }
}

} // namespace

extern "C" void kernel_launch(void* const* d_in, const int* in_sizes, int n_in,
                              void* d_out, int out_size, void* d_ws, size_t ws_size,
                              hipStream_t stream) {
    const float* x    = (const float*)d_in[0];
    const float* k1   = (const float*)d_in[1];
    const float* k2   = (const float*)d_in[2];
    const float* bias = (const float*)d_in[3];
    float* out        = (float*)d_out;

    const int nblocks = Bc * HOc * 8;   // 8 * 30 * 8 = 1920 (wo tiles of 4)
    bipolar_morph2d<<<dim3(nblocks), dim3(256), 0, stream>>>(x, k1, k2, bias, out);
}